// Round 8
// baseline (161.489 us; speedup 1.0000x reference)
//
#include <hip/hip_runtime.h>
#include <hip/hip_bf16.h>
#include <cmath>

#define NB 16384   // batch rows
#define NK 512     // in features
#define NO 1024    // out features (centres)
#define NC 5       // classes
#define NSL 16     // partial slices = 4 bn-blocks x 4 wave-cols

typedef float f32x4 __attribute__((ext_vector_type(4)));
typedef short s16x8 __attribute__((ext_vector_type(8)));

__device__ inline short f2bf(float f) {
    union { __hip_bfloat16 h; short s; } u;
    u.h = __float2bfloat16(f);
    return u.s;
}

// ---------------------------------------------------------------------------
// Kernel 1: fused row sum-of-squares (f32) + bf16 conversion of X and C.
// ---------------------------------------------------------------------------
__global__ void prep_bf16(const float* __restrict__ x, const float* __restrict__ c,
                          short* __restrict__ xbf, short* __restrict__ cbf,
                          float* __restrict__ x2, float* __restrict__ c2) {
    int gw   = (blockIdx.x * blockDim.x + threadIdx.x) >> 6;
    int lane = threadIdx.x & 63;
    if (gw >= NB + NO) return;
    bool isX = gw < NB;
    const float* src = isX ? (x + (size_t)gw * NK) : (c + (size_t)(gw - NB) * NK);
    short*       dst = isX ? (xbf + (size_t)gw * NK) : (cbf + (size_t)(gw - NB) * NK);
    f32x4 v0 = *(const f32x4*)(src + lane * 8);
    f32x4 v1 = *(const f32x4*)(src + lane * 8 + 4);
    s16x8 o;
    float s = 0.f;
#pragma unroll
    for (int j = 0; j < 4; ++j) {
        s += v0[j] * v0[j] + v1[j] * v1[j];
        o[j]     = f2bf(v0[j]);
        o[4 + j] = f2bf(v1[j]);
    }
    *(s16x8*)(dst + lane * 8) = o;
#pragma unroll
    for (int off = 1; off < 64; off <<= 1) s += __shfl_xor(s, off);
    if (lane == 0) {
        if (isX) x2[gw] = s;
        else     c2[gw - NB] = s;
    }
}

// Standalone prep for the fallback path.
__global__ void prep_f32(const float* __restrict__ x, const float* __restrict__ c,
                         float* __restrict__ x2, float* __restrict__ c2) {
    int gw   = (blockIdx.x * blockDim.x + threadIdx.x) >> 6;
    int lane = threadIdx.x & 63;
    if (gw >= NB + NO) return;
    const float* src = (gw < NB) ? (x + (size_t)gw * NK)
                                 : (c + (size_t)(gw - NB) * NK);
    f32x4 v0 = *(const f32x4*)(src + lane * 8);
    f32x4 v1 = *(const f32x4*)(src + lane * 8 + 4);
    float s = 0.f;
#pragma unroll
    for (int j = 0; j < 4; ++j) s += v0[j] * v0[j] + v1[j] * v1[j];
#pragma unroll
    for (int off = 1; off < 64; off <<= 1) s += __shfl_xor(s, off);
    if (lane == 0) {
        if (gw < NB) x2[gw] = s;
        else         c2[gw - NB] = s;
    }
}

// ---------------------------------------------------------------------------
// Kernel 2 (fallback only): out[b][n] = fc_b[n].
// ---------------------------------------------------------------------------
__global__ void init_out(float* __restrict__ out, const float* __restrict__ fcb) {
    int i = blockIdx.x * blockDim.x + threadIdx.x;
    if (i < NB * NC) out[i] = fcb[i % NC];
}

// ---------------------------------------------------------------------------
// Kernel 4: sum 16 partial slices + bias -> out.  part[NSL][NB*NC].
// ---------------------------------------------------------------------------
__global__ void reduce_out(const float* __restrict__ part,
                           const float* __restrict__ fcb,
                           float* __restrict__ out) {
    int i = blockIdx.x * blockDim.x + threadIdx.x;   // group of 4 f32
    if (i >= NB * NC / 4) return;
    f32x4 s = {0.f, 0.f, 0.f, 0.f};
#pragma unroll
    for (int sl = 0; sl < NSL; ++sl)
        s += *(const f32x4*)(part + (size_t)sl * NB * NC + i * 4);
    f32x4 o;
#pragma unroll
    for (int j = 0; j < 4; ++j) o[j] = s[j] + fcb[(i * 4 + j) % NC];
    *(f32x4*)(out + i * 4) = o;
}

// ---------------------------------------------------------------------------
// Kernel 3 (main): BARRIER-FREE direct-from-L2 MFMA GEMM. No LDS at all.
// The 16x16x32 fragment (row = lane&15, 16 contiguous bytes of K per lane)
// is loaded straight from the row-major bf16 panels with one
// global_load_dwordx4 per fragment; A/B panels are L2-resident (3 MB/XCD
// with the chunked remap). Block = 512 thr = 8 waves (2M x 4N), per-wave
// 64x64 C (acc 64 VGPR). Per K-32 step: 8 frag loads + 16 MFMA, no sync.
// Latency hidden by 16 waves/CU (LDS=0, VGPR<=128 via launch_bounds).
// Waves with the same wm read IDENTICAL A addresses (wn-independent) ->
// L1 capture cuts A L2 traffic up to 4x.
// ---------------------------------------------------------------------------
__global__ __launch_bounds__(512, 4)
void rbf_gemm_dl(const short* __restrict__ Abf, const short* __restrict__ Bbf,
                 const float* __restrict__ x2, const float* __restrict__ c2,
                 const float* __restrict__ ls, const float* __restrict__ fcw,
                 float* __restrict__ part) {
    const int t    = threadIdx.x;
    const int lane = t & 63;
    const int wave = t >> 6;
    const int wm   = wave >> 2, wn = wave & 3;   // 2M x 4N wave grid
    const int lr   = lane & 15, kg = lane >> 4;

    // XCD-chunked remap: 512 blocks, 64 consecutive wg per XCD
    // -> per XCD: 16 bm x 4 bn => A-chunk 2MB + B 1MB in 4MB L2.
    const int orig = blockIdx.x;
    const int wg   = (orig & 7) * 64 + (orig >> 3);
    const int bm = wg >> 2, bn = wg & 3;         // tile 128M x 256N

    // fragment base pointers (16B-aligned; K advances via offset:kt*64B)
    const short* pA[4];
    const short* pB[4];
#pragma unroll
    for (int i = 0; i < 4; ++i) {
        pA[i] = Abf + (size_t)(bm * 128 + wm * 64 + i * 16 + lr) * NK + kg * 8;
        pB[i] = Bbf + (size_t)(bn * 256 + wn * 64 + i * 16 + lr) * NK + kg * 8;
    }

    f32x4 acc[4][4];
#pragma unroll
    for (int i = 0; i < 4; ++i)
#pragma unroll
        for (int j = 0; j < 4; ++j)
#pragma unroll
            for (int k = 0; k < 4; ++k) acc[i][j][k] = 0.f;

#pragma unroll
    for (int kt = 0; kt < NK / 32; ++kt) {
        s16x8 af[4], bf[4];
#pragma unroll
        for (int mi = 0; mi < 4; ++mi) af[mi] = *(const s16x8*)(pA[mi] + kt * 32);
#pragma unroll
        for (int ni = 0; ni < 4; ++ni) bf[ni] = *(const s16x8*)(pB[ni] + kt * 32);
#pragma unroll
        for (int mi = 0; mi < 4; ++mi)
#pragma unroll
            for (int ni = 0; ni < 4; ++ni)
                acc[mi][ni] = __builtin_amdgcn_mfma_f32_16x16x32_bf16(
                    af[mi], bf[ni], acc[mi][ni], 0, 0, 0);
    }

    // ---- epilogue: sq -> basis -> per-wave 64-col partial -> slice store ---
    // C frag (16x16x32): col = lane&15, row = (lane>>4)*4 + reg  [m89/m91]
    const int growb0 = bm * 128 + wm * 64 + kg * 4;   // + mi*16 + r
    const int gcol0  = bn * 256 + wn * 64 + lr;       // + ni*16
    float* slice = part + (size_t)(bn * 4 + wn) * NB * NC;

    float c2v[4], invs2[4], w[4][5];
#pragma unroll
    for (int ni = 0; ni < 4; ++ni) {
        int gc = gcol0 + ni * 16;
        c2v[ni]   = c2[gc];
        invs2[ni] = __expf(-2.f * ls[gc]);   // 1/sigma^2
#pragma unroll
        for (int n = 0; n < 5; ++n) w[ni][n] = fcw[n * NO + gc];
    }

#pragma unroll
    for (int mi = 0; mi < 4; ++mi) {
        float rs[4][5];
#pragma unroll
        for (int r = 0; r < 4; ++r)
#pragma unroll
            for (int n = 0; n < 5; ++n) rs[r][n] = 0.f;

#pragma unroll
        for (int r = 0; r < 4; ++r) {
            float x2v = x2[growb0 + mi * 16 + r];
#pragma unroll
            for (int ni = 0; ni < 4; ++ni) {
                float sq    = fmaxf(x2v + c2v[ni] - 2.f * acc[mi][ni][r], 0.f);
                float basis = __expf(-sq * invs2[ni]);
#pragma unroll
                for (int n = 0; n < 5; ++n) rs[r][n] += basis * w[ni][n];
            }
        }
#pragma unroll
        for (int off = 1; off < 16; off <<= 1)
#pragma unroll
            for (int r = 0; r < 4; ++r)
#pragma unroll
                for (int n = 0; n < 5; ++n) rs[r][n] += __shfl_xor(rs[r][n], off);

        if (lr == 0) {
            float* dst = slice + (size_t)(growb0 + mi * 16) * NC;
            f32x4 v0 = {rs[0][0], rs[0][1], rs[0][2], rs[0][3]};
            f32x4 v1 = {rs[0][4], rs[1][0], rs[1][1], rs[1][2]};
            f32x4 v2 = {rs[1][3], rs[1][4], rs[2][0], rs[2][1]};
            f32x4 v3 = {rs[2][2], rs[2][3], rs[2][4], rs[3][0]};
            f32x4 v4 = {rs[3][1], rs[3][2], rs[3][3], rs[3][4]};
            *(f32x4*)(dst)      = v0;
            *(f32x4*)(dst + 4)  = v1;
            *(f32x4*)(dst + 8)  = v2;
            *(f32x4*)(dst + 12) = v3;
            *(f32x4*)(dst + 16) = v4;
        }
    }
}

// ---------------------------------------------------------------------------
// Fallback (ws too small): f32 reg-staged, atomic epilogue (round-1 proven).
// ---------------------------------------------------------------------------
__device__ inline void rbf_epilogue_atomic(f32x4 acc[4][4],
                                           const float* __restrict__ x2,
                                           const float* __restrict__ c2,
                                           const float* __restrict__ ls,
                                           const float* __restrict__ fcw,
                                           float* __restrict__ out,
                                           int bm, int bn, int wr, int wc,
                                           int lc, int kg) {
    const int growb0 = bm * 128 + wr * 64 + kg * 4;
    const int gcol0  = bn * 128 + wc * 64 + lc;
    float c2v[4], invs2[4], w[4][5];
#pragma unroll
    for (int ni = 0; ni < 4; ++ni) {
        int gc = gcol0 + ni * 16;
        c2v[ni]   = c2[gc];
        invs2[ni] = expf(-2.f * ls[gc]);
#pragma unroll
        for (int n = 0; n < 5; ++n) w[ni][n] = fcw[n * NO + gc];
    }
#pragma unroll
    for (int mi = 0; mi < 4; ++mi) {
        float rs[4][5];
#pragma unroll
        for (int r = 0; r < 4; ++r)
#pragma unroll
            for (int n = 0; n < 5; ++n) rs[r][n] = 0.f;
#pragma unroll
        for (int r = 0; r < 4; ++r) {
            float x2v = x2[growb0 + mi * 16 + r];
#pragma unroll
            for (int ni = 0; ni < 4; ++ni) {
                float sq    = fmaxf(x2v + c2v[ni] - 2.f * acc[mi][ni][r], 0.f);
                float basis = expf(-sq * invs2[ni]);
#pragma unroll
                for (int n = 0; n < 5; ++n) rs[r][n] += basis * w[ni][n];
            }
        }
#pragma unroll
        for (int off = 1; off < 16; off <<= 1)
#pragma unroll
            for (int r = 0; r < 4; ++r)
#pragma unroll
                for (int n = 0; n < 5; ++n) rs[r][n] += __shfl_xor(rs[r][n], off);
        if (lc == 0) {
#pragma unroll
            for (int r = 0; r < 4; ++r) {
                int grow = growb0 + mi * 16 + r;
#pragma unroll
                for (int n = 0; n < 5; ++n)
                    atomicAdd(&out[(size_t)grow * NC + n], rs[r][n]);
            }
        }
    }
}

__global__ __launch_bounds__(256)
void rbf_gemm_f32(const float* __restrict__ X, const float* __restrict__ Cn,
                  const float* __restrict__ x2, const float* __restrict__ c2,
                  const float* __restrict__ ls, const float* __restrict__ fcw,
                  float* __restrict__ out) {
    __shared__ short As[128 * 40];
    __shared__ short Bs[128 * 40];

    const int t    = threadIdx.x;
    const int lane = t & 63, wave = t >> 6;
    const int wr = wave >> 1, wc = wave & 1;
    const int lc = lane & 15, kg = lane >> 4;
    const int bn = blockIdx.x & 7, bm = blockIdx.x >> 3;

    const int srow = t >> 1, shalf = t & 1;
    const float* pA = X  + (size_t)(bm * 128 + srow) * NK + shalf * 16;
    const float* pB = Cn + (size_t)(bn * 128 + srow) * NK + shalf * 16;
    const int sbase = srow * 40 + shalf * 16;

    f32x4 ra[4], rb[4];
#pragma unroll
    for (int i = 0; i < 4; ++i) {
        ra[i] = *(const f32x4*)(pA + i * 4);
        rb[i] = *(const f32x4*)(pB + i * 4);
    }

    f32x4 acc[4][4];
#pragma unroll
    for (int i = 0; i < 4; ++i)
#pragma unroll
        for (int j = 0; j < 4; ++j)
#pragma unroll
            for (int k = 0; k < 4; ++k) acc[i][j][k] = 0.f;

    const short* Ab = As + (wr * 64 + lc) * 40 + kg * 8;
    const short* Bb = Bs + (wc * 64 + lc) * 40 + kg * 8;

    for (int kt = 0; kt < NK / 32; ++kt) {
        __syncthreads();
        s16x8 va0, va1, vb0, vb1;
#pragma unroll
        for (int i = 0; i < 8; ++i) {
            va0[i] = f2bf(ra[i >> 2][i & 3]);
            va1[i] = f2bf(ra[2 + (i >> 2)][i & 3]);
            vb0[i] = f2bf(rb[i >> 2][i & 3]);
            vb1[i] = f2bf(rb[2 + (i >> 2)][i & 3]);
        }
        *(s16x8*)&As[sbase]     = va0;
        *(s16x8*)&As[sbase + 8] = va1;
        *(s16x8*)&Bs[sbase]     = vb0;
        *(s16x8*)&Bs[sbase + 8] = vb1;
        __syncthreads();

        if (kt + 1 < NK / 32) {
            const float* qA = pA + (kt + 1) * 32;
            const float* qB = pB + (kt + 1) * 32;
#pragma unroll
            for (int i = 0; i < 4; ++i) {
                ra[i] = *(const f32x4*)(qA + i * 4);
                rb[i] = *(const f32x4*)(qB + i * 4);
            }
        }

        s16x8 af[4], bfv[4];
#pragma unroll
        for (int mi = 0; mi < 4; ++mi) af[mi]  = *(const s16x8*)(Ab + mi * 16 * 40);
#pragma unroll
        for (int ni = 0; ni < 4; ++ni) bfv[ni] = *(const s16x8*)(Bb + ni * 16 * 40);
#pragma unroll
        for (int mi = 0; mi < 4; ++mi)
#pragma unroll
            for (int ni = 0; ni < 4; ++ni)
                acc[mi][ni] = __builtin_amdgcn_mfma_f32_16x16x32_bf16(
                    af[mi], bfv[ni], acc[mi][ni], 0, 0, 0);
    }

    rbf_epilogue_atomic(acc, x2, c2, ls, fcw, out, bm, bn, wr, wc, lc, kg);
}

// ---------------------------------------------------------------------------
extern "C" void kernel_launch(void* const* d_in, const int* in_sizes, int n_in,
                              void* d_out, int out_size, void* d_ws, size_t ws_size,
                              hipStream_t stream) {
    const float* X   = (const float*)d_in[0];   // [16384, 512]
    const float* Cn  = (const float*)d_in[1];   // [1024, 512]
    const float* ls  = (const float*)d_in[2];   // [1024]
    const float* fcw = (const float*)d_in[3];   // [5, 1024]
    const float* fcb = (const float*)d_in[4];   // [5]
    float* out = (float*)d_out;                 // [16384, 5]

    const size_t xbf_e  = (size_t)NB * NK;          // shorts
    const size_t cbf_e  = (size_t)NO * NK;          // shorts
    const size_t part_e = (size_t)NSL * NB * NC;    // f32
    const size_t need   = (xbf_e + cbf_e) * 2 + (NB + NO) * 4 + part_e * 4;

    if (ws_size >= need) {
        short* xbf  = (short*)d_ws;
        short* cbf  = xbf + xbf_e;
        float* x2   = (float*)(cbf + cbf_e);
        float* c2   = x2 + NB;
        float* part = c2 + NO;
        prep_bf16<<<(NB + NO + 3) / 4, 256, 0, stream>>>(X, Cn, xbf, cbf, x2, c2);
        rbf_gemm_dl<<<(NB / 128) * (NO / 256), 512, 0, stream>>>(xbf, cbf, x2, c2, ls, fcw, part);
        reduce_out<<<(NB * NC / 4 + 255) / 256, 256, 0, stream>>>(part, fcb, out);
    } else {
        float* x2 = (float*)d_ws;
        float* c2 = x2 + NB;
        init_out<<<(NB * NC + 255) / 256, 256, 0, stream>>>(out, fcb);
        prep_f32<<<(NB + NO + 3) / 4, 256, 0, stream>>>(X, Cn, x2, c2);
        rbf_gemm_f32<<<(NO / 128) * (NB / 128), 256, 0, stream>>>(X, Cn, x2, c2, ls, fcw, out);
    }
}

// Round 11
// 112.241 us; speedup vs baseline: 1.4388x; 1.4388x over previous
//
#include <hip/hip_runtime.h>
#include <hip/hip_bf16.h>
#include <cmath>

#define NB 16384   // batch rows
#define NK 512     // in features
#define NO 1024    // out features (centres)
#define NC 5       // classes
#define NSL 16     // partial slices = 8 bn-blocks x 2 wave-cols
#define NT 4       // K-tiles (NK/128)

typedef float f32x4 __attribute__((ext_vector_type(4)));
typedef short s16x8 __attribute__((ext_vector_type(8)));
typedef int   i32x4 __attribute__((ext_vector_type(4)));
typedef int   i32x8 __attribute__((ext_vector_type(8)));
#define AS1 __attribute__((address_space(1)))
#define AS3 __attribute__((address_space(3)))

__device__ inline short f2bf(float f) {
    union { __hip_bfloat16 h; short s; } u;
    u.h = __float2bfloat16(f);
    return u.s;
}

// Software f32 -> OCP e4m3fn (round-half-up, FTZ below 2^-6, clamp 448).
// Error budget is enormous here: sq ~= 1024 +- 64, basis = exp(-sq) == 0.
__device__ inline unsigned int f32_to_e4m3(float f) {
    unsigned int s = (__float_as_uint(f) >> 24) & 0x80;
    float a = fabsf(f);
    if (a < 0.015625f) return s;              // flush tiny (err <= 2^-6)
    if (a > 440.f) return s | 0x7E;           // clamp to 448 (never for N(0,1))
    unsigned int ub = __float_as_uint(a) + 0x00080000u;  // round at 3-bit mant
    int e = (int)(ub >> 23) - 127;            // e in [-6, 8]
    unsigned int m = (ub >> 20) & 7u;
    return s | ((unsigned int)(e + 7) << 3) | m;
}

// ---------------------------------------------------------------------------
// Kernel 1: fused row sum-of-squares (f32, exact) + fp8 e4m3 quantization.
// One wave per row: 512 f32 = 8 per lane -> 8 fp8 bytes per lane.
// ---------------------------------------------------------------------------
__global__ void prep_fp8(const float* __restrict__ x, const float* __restrict__ c,
                         unsigned char* __restrict__ xq, unsigned char* __restrict__ cq,
                         float* __restrict__ x2, float* __restrict__ c2) {
    int gw   = (blockIdx.x * blockDim.x + threadIdx.x) >> 6;
    int lane = threadIdx.x & 63;
    if (gw >= NB + NO) return;
    bool isX = gw < NB;
    const float*   src = isX ? (x + (size_t)gw * NK) : (c + (size_t)(gw - NB) * NK);
    unsigned char* dst = isX ? (xq + (size_t)gw * NK) : (cq + (size_t)(gw - NB) * NK);
    f32x4 v0 = *(const f32x4*)(src + lane * 8);
    f32x4 v1 = *(const f32x4*)(src + lane * 8 + 4);
    float s = 0.f;
    unsigned int w0 = 0, w1 = 0;
#pragma unroll
    for (int j = 0; j < 4; ++j) {
        s += v0[j] * v0[j] + v1[j] * v1[j];
        w0 |= f32_to_e4m3(v0[j]) << (8 * j);
        w1 |= f32_to_e4m3(v1[j]) << (8 * j);
    }
    uint2 o; o.x = w0; o.y = w1;
    *(uint2*)(dst + lane * 8) = o;
#pragma unroll
    for (int off = 1; off < 64; off <<= 1) s += __shfl_xor(s, off);
    if (lane == 0) {
        if (isX) x2[gw] = s;
        else     c2[gw - NB] = s;
    }
}

// Standalone prep for the fallback path.
__global__ void prep_f32(const float* __restrict__ x, const float* __restrict__ c,
                         float* __restrict__ x2, float* __restrict__ c2) {
    int gw   = (blockIdx.x * blockDim.x + threadIdx.x) >> 6;
    int lane = threadIdx.x & 63;
    if (gw >= NB + NO) return;
    const float* src = (gw < NB) ? (x + (size_t)gw * NK)
                                 : (c + (size_t)(gw - NB) * NK);
    f32x4 v0 = *(const f32x4*)(src + lane * 8);
    f32x4 v1 = *(const f32x4*)(src + lane * 8 + 4);
    float s = 0.f;
#pragma unroll
    for (int j = 0; j < 4; ++j) s += v0[j] * v0[j] + v1[j] * v1[j];
#pragma unroll
    for (int off = 1; off < 64; off <<= 1) s += __shfl_xor(s, off);
    if (lane == 0) {
        if (gw < NB) x2[gw] = s;
        else         c2[gw - NB] = s;
    }
}

// ---------------------------------------------------------------------------
// Kernel 2 (fallback only): out[b][n] = fc_b[n].
// ---------------------------------------------------------------------------
__global__ void init_out(float* __restrict__ out, const float* __restrict__ fcb) {
    int i = blockIdx.x * blockDim.x + threadIdx.x;
    if (i < NB * NC) out[i] = fcb[i % NC];
}

// ---------------------------------------------------------------------------
// Kernel 4: sum 16 partial slices + bias -> out.  part[NSL][NB*NC].
// ---------------------------------------------------------------------------
__global__ void reduce_out(const float* __restrict__ part,
                           const float* __restrict__ fcb,
                           float* __restrict__ out) {
    int i = blockIdx.x * blockDim.x + threadIdx.x;   // group of 4 f32
    if (i >= NB * NC / 4) return;
    f32x4 s = {0.f, 0.f, 0.f, 0.f};
#pragma unroll
    for (int sl = 0; sl < NSL; ++sl)
        s += *(const f32x4*)(part + (size_t)sl * NB * NC + i * 4);
    f32x4 o;
#pragma unroll
    for (int j = 0; j < 4; ++j) o[j] = s[j] + fcb[(i * 4 + j) % NC];
    *(f32x4*)(out + i * 4) = o;
}

// ---------------------------------------------------------------------------
// Kernel 3 (main): MX-fp8 GEMM with unit scales. 128x128 tile, 256 thr =
// 4 waves (2x2), per-wave 64x64. K=512 -> only NT=4 K-tiles of BK=128 via
// v_mfma_scale_f32_16x16x128_f8f6f4 (scale e8m0=127 => x1.0): 4x fewer MFMA
// than bf16-K32 and half the staging bytes. 2 LDS dbufs (64KB) -> 2 blk/CU.
// LDS swizzle: physical 16B chunk c of row r holds logical chunk c^(r&7)
// (pre-swizzled global src + linear gload_lds dest + swizzled ds_read);
// reads spread 8 lanes per chunk-slot group = balanced (R6-verified model).
// ---------------------------------------------------------------------------
__global__ __launch_bounds__(256, 2)
void rbf_gemm_fp8(const unsigned char* __restrict__ Aq, const unsigned char* __restrict__ Bq,
                  const float* __restrict__ x2, const float* __restrict__ c2,
                  const float* __restrict__ ls, const float* __restrict__ fcw,
                  float* __restrict__ part) {
    __shared__ unsigned char As[2][16384];   // 128 rows x 128 B
    __shared__ unsigned char Bs[2][16384];

    const int t    = threadIdx.x;
    const int lane = t & 63, wave = t >> 6;
    const int wr = wave >> 1, wc = wave & 1;     // 2x2 wave grid
    const int lr = lane & 15, kg = lane >> 4;

    // XCD-chunked remap: 1024 blocks, 128 consecutive wg per XCD
    // -> per XCD: 16 bm x 8 bn => A-chunk 1MB + B 0.5MB in 4MB L2.
    const int orig = blockIdx.x;
    const int wg   = (orig & 7) * 128 + (orig >> 3);
    const int bm = wg >> 3, bn = wg & 7;

    // staging: physical chunk p = j*256 + t; row = p>>3; logical chunk
    // lc = (p&7) ^ (row&7); source = row, K-bytes lc*16 within the tile.
    const unsigned char* gA[4];
    const unsigned char* gB[4];
#pragma unroll
    for (int j = 0; j < 4; ++j) {
        int p   = j * 256 + t;
        int row = p >> 3;
        int lc  = (p & 7) ^ (row & 7);
        gA[j] = Aq + (size_t)(bm * 128 + row) * NK + lc * 16;
        gB[j] = Bq + (size_t)(bn * 128 + row) * NK + lc * 16;
    }

#define STAGE(buf, kt) do {                                                     \
    _Pragma("unroll")                                                           \
    for (int j = 0; j < 4; ++j) {                                               \
        __builtin_amdgcn_global_load_lds(                                       \
            (const AS1 unsigned int*)(gA[j] + (kt) * 128),                      \
            (AS3 unsigned int*)(&As[buf][j * 4096 + wave * 1024]), 16, 0, 0);   \
        __builtin_amdgcn_global_load_lds(                                       \
            (const AS1 unsigned int*)(gB[j] + (kt) * 128),                      \
            (AS3 unsigned int*)(&Bs[buf][j * 4096 + wave * 1024]), 16, 0, 0);   \
    }                                                                           \
} while (0)

    // fragment read: 32 B = 2 x b128 at swizzled chunks c0, c0^1.
    const int c0 = (kg * 2) ^ (lr & 7);

#define RD_FRAG(dst, base, rowoff) do {                                         \
    i32x4 lo = *(const i32x4*)((base) + (rowoff) + (size_t)(c0 * 16));          \
    i32x4 hi = *(const i32x4*)((base) + (rowoff) + (size_t)((c0 ^ 1) * 16));    \
    dst = (i32x8){lo[0], lo[1], lo[2], lo[3], hi[0], hi[1], hi[2], hi[3]};      \
} while (0)

    f32x4 acc[4][4];
#pragma unroll
    for (int i = 0; i < 4; ++i)
#pragma unroll
        for (int j = 0; j < 4; ++j)
#pragma unroll
            for (int k = 0; k < 4; ++k) acc[i][j][k] = 0.f;

    const int SC = 0x7F7F7F7F;   // e8m0 = 127 in every byte -> scale = 1.0

    STAGE(0, 0);
    __syncthreads();
#pragma unroll
    for (int kt = 0; kt < NT; ++kt) {
        const int buf = kt & 1;
        if (kt + 1 < NT) STAGE(buf ^ 1, kt + 1);   // flies during this body
        i32x8 af[4], bf[4];
#pragma unroll
        for (int ni = 0; ni < 4; ++ni)
            RD_FRAG(bf[ni], Bs[buf], (wc * 64 + ni * 16 + lr) * 128);
#pragma unroll
        for (int mi = 0; mi < 4; ++mi)
            RD_FRAG(af[mi], As[buf], (wr * 64 + mi * 16 + lr) * 128);
        __builtin_amdgcn_s_setprio(1);
#pragma unroll
        for (int mi = 0; mi < 4; ++mi)
#pragma unroll
            for (int ni = 0; ni < 4; ++ni)
                acc[mi][ni] = __builtin_amdgcn_mfma_scale_f32_16x16x128_f8f6f4(
                    af[mi], bf[ni], acc[mi][ni],
                    0, 0,            // cbsz = fp8 (A), blgp = fp8 (B)
                    0, SC,           // opsel_a, scale_a (x1.0)
                    0, SC);          // opsel_b, scale_b (x1.0)
        __builtin_amdgcn_s_setprio(0);
        if (kt + 1 < NT) __syncthreads();          // drains vmcnt for t+1
    }
#undef STAGE
#undef RD_FRAG

    // ---- epilogue: sq -> basis -> per-wave 64-col partial -> slice store ---
    // C frag (16x16 shapes, dtype-independent): col = lane&15,
    // row = (lane>>4)*4 + reg   [m89/m91/m121-128]
    const int growb0 = bm * 128 + wr * 64 + kg * 4;   // + mi*16 + r
    const int gcol0  = bn * 128 + wc * 64 + lr;       // + ni*16
    float* slice = part + (size_t)(bn * 2 + wc) * NB * NC;

    float c2v[4], invs2[4], w[4][5];
#pragma unroll
    for (int ni = 0; ni < 4; ++ni) {
        int gc = gcol0 + ni * 16;
        c2v[ni]   = c2[gc];
        invs2[ni] = __expf(-2.f * ls[gc]);   // 1/sigma^2
#pragma unroll
        for (int n = 0; n < 5; ++n) w[ni][n] = fcw[n * NO + gc];
    }

#pragma unroll
    for (int mi = 0; mi < 4; ++mi) {
        float rs[4][5];
#pragma unroll
        for (int r = 0; r < 4; ++r)
#pragma unroll
            for (int n = 0; n < 5; ++n) rs[r][n] = 0.f;

#pragma unroll
        for (int r = 0; r < 4; ++r) {
            float x2v = x2[growb0 + mi * 16 + r];
#pragma unroll
            for (int ni = 0; ni < 4; ++ni) {
                float sq    = fmaxf(x2v + c2v[ni] - 2.f * acc[mi][ni][r], 0.f);
                float basis = __expf(-sq * invs2[ni]);
#pragma unroll
                for (int n = 0; n < 5; ++n) rs[r][n] += basis * w[ni][n];
            }
        }
#pragma unroll
        for (int off = 1; off < 16; off <<= 1)
#pragma unroll
            for (int r = 0; r < 4; ++r)
#pragma unroll
                for (int n = 0; n < 5; ++n) rs[r][n] += __shfl_xor(rs[r][n], off);

        if (lr == 0) {
            float* dst = slice + (size_t)(growb0 + mi * 16) * NC;
            f32x4 v0 = {rs[0][0], rs[0][1], rs[0][2], rs[0][3]};
            f32x4 v1 = {rs[0][4], rs[1][0], rs[1][1], rs[1][2]};
            f32x4 v2 = {rs[1][3], rs[1][4], rs[2][0], rs[2][1]};
            f32x4 v3 = {rs[2][2], rs[2][3], rs[2][4], rs[3][0]};
            f32x4 v4 = {rs[3][1], rs[3][2], rs[3][3], rs[3][4]};
            *(f32x4*)(dst)      = v0;
            *(f32x4*)(dst + 4)  = v1;
            *(f32x4*)(dst + 8)  = v2;
            *(f32x4*)(dst + 12) = v3;
            *(f32x4*)(dst + 16) = v4;
        }
    }
}

// ---------------------------------------------------------------------------
// Fallback (ws too small): f32 reg-staged, atomic epilogue (round-1 proven).
// ---------------------------------------------------------------------------
__device__ inline void rbf_epilogue_atomic(f32x4 acc[4][4],
                                           const float* __restrict__ x2,
                                           const float* __restrict__ c2,
                                           const float* __restrict__ ls,
                                           const float* __restrict__ fcw,
                                           float* __restrict__ out,
                                           int bm, int bn, int wr, int wc,
                                           int lc, int kg) {
    const int growb0 = bm * 128 + wr * 64 + kg * 4;
    const int gcol0  = bn * 128 + wc * 64 + lc;
    float c2v[4], invs2[4], w[4][5];
#pragma unroll
    for (int ni = 0; ni < 4; ++ni) {
        int gc = gcol0 + ni * 16;
        c2v[ni]   = c2[gc];
        invs2[ni] = expf(-2.f * ls[gc]);
#pragma unroll
        for (int n = 0; n < 5; ++n) w[ni][n] = fcw[n * NO + gc];
    }
#pragma unroll
    for (int mi = 0; mi < 4; ++mi) {
        float rs[4][5];
#pragma unroll
        for (int r = 0; r < 4; ++r)
#pragma unroll
            for (int n = 0; n < 5; ++n) rs[r][n] = 0.f;
#pragma unroll
        for (int r = 0; r < 4; ++r) {
            float x2v = x2[growb0 + mi * 16 + r];
#pragma unroll
            for (int ni = 0; ni < 4; ++ni) {
                float sq    = fmaxf(x2v + c2v[ni] - 2.f * acc[mi][ni][r], 0.f);
                float basis = expf(-sq * invs2[ni]);
#pragma unroll
                for (int n = 0; n < 5; ++n) rs[r][n] += basis * w[ni][n];
            }
        }
#pragma unroll
        for (int off = 1; off < 16; off <<= 1)
#pragma unroll
            for (int r = 0; r < 4; ++r)
#pragma unroll
                for (int n = 0; n < 5; ++n) rs[r][n] += __shfl_xor(rs[r][n], off);
        if (lc == 0) {
#pragma unroll
            for (int r = 0; r < 4; ++r) {
                int grow = growb0 + mi * 16 + r;
#pragma unroll
                for (int n = 0; n < 5; ++n)
                    atomicAdd(&out[(size_t)grow * NC + n], rs[r][n]);
            }
        }
    }
}

__global__ __launch_bounds__(256)
void rbf_gemm_f32(const float* __restrict__ X, const float* __restrict__ Cn,
                  const float* __restrict__ x2, const float* __restrict__ c2,
                  const float* __restrict__ ls, const float* __restrict__ fcw,
                  float* __restrict__ out) {
    __shared__ short As[128 * 40];
    __shared__ short Bs[128 * 40];

    const int t    = threadIdx.x;
    const int lane = t & 63, wave = t >> 6;
    const int wr = wave >> 1, wc = wave & 1;
    const int lc = lane & 15, kg = lane >> 4;
    const int bn = blockIdx.x & 7, bm = blockIdx.x >> 3;

    const int srow = t >> 1, shalf = t & 1;
    const float* pA = X  + (size_t)(bm * 128 + srow) * NK + shalf * 16;
    const float* pB = Cn + (size_t)(bn * 128 + srow) * NK + shalf * 16;
    const int sbase = srow * 40 + shalf * 16;

    f32x4 ra[4], rb[4];
#pragma unroll
    for (int i = 0; i < 4; ++i) {
        ra[i] = *(const f32x4*)(pA + i * 4);
        rb[i] = *(const f32x4*)(pB + i * 4);
    }

    f32x4 acc[4][4];
#pragma unroll
    for (int i = 0; i < 4; ++i)
#pragma unroll
        for (int j = 0; j < 4; ++j)
#pragma unroll
            for (int k = 0; k < 4; ++k) acc[i][j][k] = 0.f;

    const short* Ab = As + (wr * 64 + lc) * 40 + kg * 8;
    const short* Bb = Bs + (wc * 64 + lc) * 40 + kg * 8;

    for (int kt = 0; kt < NK / 32; ++kt) {
        __syncthreads();
        s16x8 va0, va1, vb0, vb1;
#pragma unroll
        for (int i = 0; i < 8; ++i) {
            va0[i] = f2bf(ra[i >> 2][i & 3]);
            va1[i] = f2bf(ra[2 + (i >> 2)][i & 3]);
            vb0[i] = f2bf(rb[i >> 2][i & 3]);
            vb1[i] = f2bf(rb[2 + (i >> 2)][i & 3]);
        }
        *(s16x8*)&As[sbase]     = va0;
        *(s16x8*)&As[sbase + 8] = va1;
        *(s16x8*)&Bs[sbase]     = vb0;
        *(s16x8*)&Bs[sbase + 8] = vb1;
        __syncthreads();

        if (kt + 1 < NK / 32) {
            const float* qA = pA + (kt + 1) * 32;
            const float* qB = pB + (kt + 1) * 32;
#pragma unroll
            for (int i = 0; i < 4; ++i) {
                ra[i] = *(const f32x4*)(qA + i * 4);
                rb[i] = *(const f32x4*)(qB + i * 4);
            }
        }

        s16x8 af[4], bfv[4];
#pragma unroll
        for (int mi = 0; mi < 4; ++mi) af[mi]  = *(const s16x8*)(Ab + mi * 16 * 40);
#pragma unroll
        for (int ni = 0; ni < 4; ++ni) bfv[ni] = *(const s16x8*)(Bb + ni * 16 * 40);
#pragma unroll
        for (int mi = 0; mi < 4; ++mi)
#pragma unroll
            for (int ni = 0; ni < 4; ++ni)
                acc[mi][ni] = __builtin_amdgcn_mfma_f32_16x16x32_bf16(
                    af[mi], bfv[ni], acc[mi][ni], 0, 0, 0);
    }

    rbf_epilogue_atomic(acc, x2, c2, ls, fcw, out, bm, bn, wr, wc, lc, kg);
}

// ---------------------------------------------------------------------------
extern "C" void kernel_launch(void* const* d_in, const int* in_sizes, int n_in,
                              void* d_out, int out_size, void* d_ws, size_t ws_size,
                              hipStream_t stream) {
    const float* X   = (const float*)d_in[0];   // [16384, 512]
    const float* Cn  = (const float*)d_in[1];   // [1024, 512]
    const float* ls  = (const float*)d_in[2];   // [1024]
    const float* fcw = (const float*)d_in[3];   // [5, 1024]
    const float* fcb = (const float*)d_in[4];   // [5]
    float* out = (float*)d_out;                 // [16384, 5]

    const size_t xq_b   = (size_t)NB * NK;          // fp8 bytes, 8.4 MB
    const size_t cq_b   = (size_t)NO * NK;          // 0.5 MB
    const size_t part_e = (size_t)NSL * NB * NC;    // f32
    const size_t need   = xq_b + cq_b + (NB + NO) * 4 + part_e * 4;

    if (ws_size >= need) {
        unsigned char* xq = (unsigned char*)d_ws;
        unsigned char* cq = xq + xq_b;
        float* x2   = (float*)(cq + cq_b);
        float* c2   = x2 + NB;
        float* part = c2 + NO;
        prep_fp8<<<(NB + NO + 3) / 4, 256, 0, stream>>>(X, Cn, xq, cq, x2, c2);
        rbf_gemm_fp8<<<(NB / 128) * (NO / 128), 256, 0, stream>>>(xq, cq, x2, c2, ls, fcw, part);
        reduce_out<<<(NB * NC / 4 + 255) / 256, 256, 0, stream>>>(part, fcb, out);
    } else {
        float* x2 = (float*)d_ws;
        float* c2 = x2 + NB;
        init_out<<<(NB * NC + 255) / 256, 256, 0, stream>>>(out, fcb);
        prep_f32<<<(NB + NO + 3) / 4, 256, 0, stream>>>(X, Cn, x2, c2);
        rbf_gemm_f32<<<(NO / 128) * (NB / 128), 256, 0, stream>>>(X, Cn, x2, c2, ls, fcw, out);
    }
}